// Round 2
// baseline (406.111 us; speedup 1.0000x reference)
//
#include <hip/hip_runtime.h>
#include <cstdint>

#define IN_DIM 45
#define ROWS 64
#define NBLK 4096          // 262144 / 64

typedef unsigned short u16;
typedef __attribute__((ext_vector_type(8))) short v8s;     // 8 x bf16 fragment
typedef __attribute__((ext_vector_type(4))) float f32x4;   // MFMA accumulator

__device__ __forceinline__ u16 f2bf(float x){
  uint32_t u = __float_as_uint(x);
  u += 0x7FFFu + ((u >> 16) & 1u);      // RNE
  return (u16)(u >> 16);
}

__device__ __forceinline__ void g2l16(const void* g, void* l){
  __builtin_amdgcn_global_load_lds(
      (const __attribute__((address_space(1))) unsigned int*)g,
      (__attribute__((address_space(3))) unsigned int*)l, 16, 0, 0);
}

// d_ws: [0,16384)  w1s bf16 [n=128][k=64] plain (k zero-padded 45..63) — read from
//                  global directly (L1-resident), no swizzle needed.
//       [16384,+65536) w2s bf16 [n=256][k=128], 16B-granule swizzled g^=(n&15)
//                  so LDS A-frag ds_read_b128 lands 2-way (free).
__global__ void prep_kernel(const float* __restrict__ w1, const float* __restrict__ w2,
                            u16* __restrict__ w1s, u16* __restrict__ w2s){
  int idx = blockIdx.x*256 + threadIdx.x;
  if (idx < 128*64){
    int n = idx >> 6, k = idx & 63;
    float v = (k < IN_DIM) ? w1[k*128 + n] : 0.f;
    w1s[idx] = f2bf(v);                          // w1s[n*64 + k]
  } else if (idx < 128*64 + 256*128){
    int t = idx - 8192;
    int n = t >> 7, k = t & 127;
    int gp = (k >> 3) ^ (n & 15);                // 16 granules/row
    w2s[(n << 7) | (gp << 3) | (k & 7)] = f2bf(w2[k*256 + n]);
  }
}

// LDS map (70912 B -> 2 blocks/CU, 8 waves):
//   [0,16384)      w2 buf0   (quarters 0,2)
//   [16384,32768)  w2 buf1   (quarters 1,3)
//   [32768,41984)  sx : x bf16 [64][72]
//   [41984,59392)  sh : hidden bf16 [64][136]
//   [59392,70912)  pose fp32 tile [64][45]
__global__ __launch_bounds__(256, 2)
void posemlp_kernel(const float* __restrict__ pose,
                    const float* __restrict__ ln1g, const float* __restrict__ ln1b,
                    const float* __restrict__ b1v,  const float* __restrict__ b2v,
                    const float* __restrict__ ln2g, const float* __restrict__ ln2b,
                    const u16* __restrict__ w1s, const u16* __restrict__ w2s,
                    float* __restrict__ out)
{
  __shared__ __align__(16) unsigned char smem[70912];
  u16*  swbuf = (u16*)smem;
  u16*  sx = (u16*)(smem + 32768);
  u16*  sh = (u16*)(smem + 41984);
  float* posel = (float*)(smem + 59392);

  const int tid = threadIdx.x;
  const int blk = blockIdx.x;

  // ---- stage pose (11520 B, HBM) + w2 quarters 0+1 (32 KB, L2) via g2l
  {
    const char* psrc = (const char*)pose + (size_t)blk * (ROWS*IN_DIM*4);
    #pragma unroll
    for (int j = 0; j < 3; ++j){
      int i = j*256 + tid;
      if (i < 720) g2l16(psrc + i*16, smem + 59392 + i*16);
    }
    const char* wsrc = (const char*)w2s;
    #pragma unroll
    for (int j = 0; j < 8; ++j){
      int i = j*256 + tid;
      g2l16(wsrc + i*16, smem + i*16);
    }
  }
  __syncthreads();                       // vmcnt(0) drain: pose + q0 + q1 valid

  // ---- LN1 (4 lanes/row, wave-local rows) -> sx bf16, K zero-padded to 64
  {
    int row = tid >> 2, p = tid & 3;
    const float* pr = posel + row*IN_DIM;
    float sum = 0.f, sq = 0.f;
    for (int k = p; k < IN_DIM; k += 4){ float v = pr[k]; sum += v; sq += v*v; }
    sum += __shfl_xor(sum, 1); sum += __shfl_xor(sum, 2);
    sq  += __shfl_xor(sq, 1);  sq  += __shfl_xor(sq, 2);
    float mu = sum * (1.f/IN_DIM);
    float rs = rsqrtf(sq * (1.f/IN_DIM) - mu*mu + 1e-5f);
    u16* xr = sx + row*72;
    for (int k = p; k < IN_DIM; k += 4)
      xr[k] = f2bf((pr[k] - mu) * rs * ln1g[k] + ln1b[k]);
    for (int k = IN_DIM + p; k < 64; k += 4) xr[k] = 0;
  }
  // no barrier: GEMM1 reads only this wave's rows (compiler orders via lgkmcnt)

  const int lane = tid & 63, wv = tid >> 6;
  const int col = lane & 15, quad = lane >> 4;

  // ---- GEMM1 (swapped: A=w1 from GLOBAL (L1-hot), B=x from LDS)
  // D[m=h][n=row]: lane reg r of tile nt -> h = nt*16+quad*4+r, row = 16wv+col
  f32x4 acc1[8];
  #pragma unroll
  for (int i = 0; i < 8; ++i) acc1[i] = (f32x4){0.f,0.f,0.f,0.f};
  {
    const u16* xa = sx + (16*wv + col)*72 + quad*8;
    v8s bx0 = *(const v8s*)(xa);
    v8s bx1 = *(const v8s*)(xa + 32);
    #pragma unroll
    for (int nt = 0; nt < 8; ++nt){
      const u16* wr = w1s + (nt*16 + col)*64 + quad*8;
      v8s a0 = *(const v8s*)(wr);
      v8s a1 = *(const v8s*)(wr + 32);
      acc1[nt] = __builtin_amdgcn_mfma_f32_16x16x32_bf16(a0, bx0, acc1[nt], 0, 0, 0);
      acc1[nt] = __builtin_amdgcn_mfma_f32_16x16x32_bf16(a1, bx1, acc1[nt], 0, 0, 0);
    }
  }
  // bias + exact GELU -> sh[row][h], 8B packed writes (wave-local rows)
  #pragma unroll
  for (int nt = 0; nt < 8; ++nt){
    float4 bb = ((const float4*)b1v)[nt*4 + quad];
    float v0 = acc1[nt][0] + bb.x, v1 = acc1[nt][1] + bb.y;
    float v2 = acc1[nt][2] + bb.z, v3 = acc1[nt][3] + bb.w;
    v0 = 0.5f*v0*(1.f + erff(v0*0.70710678118654752f));
    v1 = 0.5f*v1*(1.f + erff(v1*0.70710678118654752f));
    v2 = 0.5f*v2*(1.f + erff(v2*0.70710678118654752f));
    v3 = 0.5f*v3*(1.f + erff(v3*0.70710678118654752f));
    ushort4 pk; pk.x = f2bf(v0); pk.y = f2bf(v1); pk.z = f2bf(v2); pk.w = f2bf(v3);
    *(ushort4*)(sh + (16*wv + col)*136 + nt*16 + quad*4) = pk;
  }
  // B-fragments of hidden for GEMM2 (wave-local; compiler orders via lgkmcnt)
  v8s bh[4];
  {
    const u16* ha = sh + (16*wv + col)*136 + quad*8;
    #pragma unroll
    for (int ks = 0; ks < 4; ++ks) bh[ks] = *(const v8s*)(ha + ks*32);
  }

  // ---- GEMM2 (swapped: A=w2 from LDS dbuf, B=hidden frags in regs)
  // Quarter hq covers douts hq*64..+64 (tiles i=hq*4+ntl).
  // Barriers: after q0-MFMA (then issue q2), after q1-MFMA (then issue q3),
  // after q2-MFMA (drains q3). 3 total; loads have a full MFMA phase to land.
  f32x4 acc2[16];
  #pragma unroll
  for (int i = 0; i < 16; ++i) acc2[i] = (f32x4){0.f,0.f,0.f,0.f};
  #pragma unroll
  for (int hq = 0; hq < 4; ++hq){
    const u16* sw = swbuf + (hq & 1)*8192;
    #pragma unroll
    for (int ntl = 0; ntl < 4; ++ntl){
      const u16* wr = sw + (ntl*16 + col)*128;
      #pragma unroll
      for (int ks = 0; ks < 4; ++ks){
        v8s a = *(const v8s*)(wr + (((ks*4 + quad) ^ col) << 3));
        acc2[hq*4 + ntl] = __builtin_amdgcn_mfma_f32_16x16x32_bf16(a, bh[ks], acc2[hq*4 + ntl], 0, 0, 0);
      }
    }
    if (hq < 3) __syncthreads();
    if (hq < 2){
      const char* src = (const char*)w2s + (hq + 2)*16384;
      #pragma unroll
      for (int j = 0; j < 4; ++j){
        int i = j*256 + tid;
        g2l16(src + i*16, smem + (hq & 1)*16384 + i*16);
      }
    }
  }

  // ---- +b2, LN2 (per-lane 64 values + 2 shuffles), float4 stores
  float sum = 0.f, sq = 0.f;
  #pragma unroll
  for (int i = 0; i < 16; ++i){
    float4 bb = ((const float4*)b2v)[i*4 + quad];
    acc2[i][0] += bb.x; acc2[i][1] += bb.y; acc2[i][2] += bb.z; acc2[i][3] += bb.w;
    sum += acc2[i][0] + acc2[i][1] + acc2[i][2] + acc2[i][3];
    sq  += acc2[i][0]*acc2[i][0] + acc2[i][1]*acc2[i][1]
         + acc2[i][2]*acc2[i][2] + acc2[i][3]*acc2[i][3];
  }
  sum += __shfl_xor(sum, 16); sum += __shfl_xor(sum, 32);
  sq  += __shfl_xor(sq, 16);  sq  += __shfl_xor(sq, 32);
  float mu = sum * (1.f/256.f);
  float rs = rsqrtf(sq * (1.f/256.f) - mu*mu + 1e-5f);
  float* orow = out + (size_t)(blk*ROWS + 16*wv + col)*256;
  #pragma unroll
  for (int i = 0; i < 16; ++i){
    float4 g = ((const float4*)ln2g)[i*4 + quad];
    float4 b = ((const float4*)ln2b)[i*4 + quad];
    float4 o;
    o.x = (acc2[i][0] - mu)*rs*g.x + b.x;
    o.y = (acc2[i][1] - mu)*rs*g.y + b.y;
    o.z = (acc2[i][2] - mu)*rs*g.z + b.z;
    o.w = (acc2[i][3] - mu)*rs*g.w + b.w;
    ((float4*)orow)[i*4 + quad] = o;
  }
}

extern "C" void kernel_launch(void* const* d_in, const int* in_sizes, int n_in,
                              void* d_out, int out_size, void* d_ws, size_t ws_size,
                              hipStream_t stream){
  const float* pose = (const float*)d_in[0];
  const float* ln1g = (const float*)d_in[1];
  const float* ln1b = (const float*)d_in[2];
  const float* w1   = (const float*)d_in[3];
  const float* b1   = (const float*)d_in[4];
  const float* w2   = (const float*)d_in[5];
  const float* b2   = (const float*)d_in[6];
  const float* ln2g = (const float*)d_in[7];
  const float* ln2b = (const float*)d_in[8];
  u16* w1s = (u16*)d_ws;
  u16* w2s = (u16*)((char*)d_ws + 16384);   // needs 81920 B of d_ws
  prep_kernel<<<160, 256, 0, stream>>>(w1, w2, w1s, w2s);
  posemlp_kernel<<<NBLK, 256, 0, stream>>>(pose, ln1g, ln1b, b1, b2, ln2g, ln2b,
                                           w1s, w2s, (float*)d_out);
}